// Round 23
// baseline (236.633 us; speedup 1.0000x reference)
//
#include <hip/hip_runtime.h>
#include <hip/hip_bf16.h>
#include <math.h>

#define S_    10
#define C_    48
#define HWD   64
#define M_    512
#define PADK  4
#define PAIRS 20           // S_ * N(=2)
#define REPG  32           // diagnostic repeat: k_gather
#define REPN  64           // diagnostic repeat: k_nc (so it clears fill floor)
#define REPF  32           // diagnostic repeat: k_final

// ws layout (float offsets)
#define OFF_GY  0                         // raw y compact fp32, c-major
#define OFF_GX  491520                    // raw x compact fp32, c-major
#define OFF_MU  983040                    // 480 floats (channel MEANS)
#define OFF_CNT (OFF_MU + 480)            // 20 uint pair-arrival counters
#define OFF_ALL (OFF_CNT + 20)            // 1 uint pair-done counter
#define OFF_PL  (OFF_ALL + 1)             // 20 float pair losses
#define ZERO_N  (20 + 1 + 20)             // OFF_CNT..OFF_PL
// fragment-major bf16: per pair 32768 ushorts (64KB). 16B chunk = lane frag.
#define OFF_YK  983584
#define OFF_XK  (OFF_YK + 327680)
#define OFF_PM  (OFF_XK + 327680)         // [pair][slab][512] plain colmax

typedef __attribute__((ext_vector_type(8))) short bf16x8;
typedef __attribute__((ext_vector_type(4))) float f32x4;

__device__ __forceinline__ int gidx(int n, int c, int h, int w, int d) {
  return (((n * C_ + c) * HWD + h) * HWD + w) * HWD + d;
}

__device__ __forceinline__ unsigned short f2bf(float f) {  // RNE bf16
  unsigned u = __float_as_uint(f);
  u += 0x7FFFu + ((u >> 16) & 1u);
  return (unsigned short)(u >> 16);
}

__device__ __forceinline__ int fidx(int m, int c) {  // fragment-major ushort idx
  return ((m >> 4) << 10) + ((c >> 5) << 9) + (((c >> 3) & 3) << 7) +
         ((m & 15) << 3) + (c & 7);
}

__device__ __forceinline__ int launder_zero() {    // rule #17 anti-DCE
  int z0 = 0;
  asm volatile("" : "+v"(z0));
  return z0;
}

// ---- kernel 1: gather (xREPG diagnostic) ----------------------------------
__global__ void k_gather(const float* __restrict__ x, const float* __restrict__ y,
                         const int* __restrict__ hi, const int* __restrict__ wi,
                         const int* __restrict__ di, float* __restrict__ ws) {
  int b = blockIdx.x, t = threadIdx.x;
  int lane = t & 63, wv = t >> 6;
  __shared__ float red[4];
  int which = b >= 480;                              // 0 = y, 1 = x
  int r = which ? b - 480 : b;
  int s = r / C_, c = r % C_;
  const float* src = which ? x : y;
  int h0 = hi[s] - PADK, w0 = wi[s] - PADK, d0 = di[s] - PADK;

  for (int rep = 0; rep < REPG; ++rep) {
    __syncthreads();                                 // protect red across reps
    int z0 = launder_zero();
    if (b == 0 && t < ZERO_N) ws[OFF_CNT + t + z0] = 0.f;
    float* dst = ws + (which ? OFF_GX : OFF_GY) + (s * 96 + 2 * c) * 512 + z0;
    float sum = 0.f;
#pragma unroll
    for (int j = 0; j < 4; ++j) {
      int i = t + 256 * j;
      int n = i >> 9, m = i & 511;
      float v = src[gidx(n, c, h0 + (m >> 6), w0 + ((m >> 3) & 7), d0 + (m & 7)) + z0];
      dst[n * 512 + m] = v;
      sum += v;
    }
    if (!which) {
#pragma unroll
      for (int off = 32; off; off >>= 1) sum += __shfl_xor(sum, off);
      if (lane == 0) red[wv] = sum;
      __syncthreads();
      if (t == 0)
        ws[OFF_MU + s * C_ + c + z0] =
            (red[0] + red[1] + red[2] + red[3]) * (1.0f / 1024.0f);
    }
  }
}

// ---- kernel 2: center + normalize -> bf16 frag-major (xREPN diagnostic) ---
__global__ void k_nc(float* __restrict__ ws) {
  int g = blockIdx.x * 256 + threadIdx.x;   // 0..81919
  int col = g >> 2;
  int q = threadIdx.x & 3;
  int which = col >= 10240;                 // 0 = y, 1 = x
  int cix = which ? col - 10240 : col;
  int pair = cix >> 9, m = cix & 511;
  int s = pair >> 1, n = pair & 1;

  for (int rep = 0; rep < REPN; ++rep) {
    int z0 = launder_zero();
    const float* base =
        ws + (which ? OFF_GX : OFF_GY) + (s * 96 + n) * 512 + m + z0;
    const float* mus = ws + OFF_MU + s * C_ + z0;
    int c0 = q * 12;
    float v[12], ss = 0.f;
#pragma unroll
    for (int j = 0; j < 12; ++j) {
      v[j] = base[(c0 + j) * 1024] - mus[c0 + j];
      ss += v[j] * v[j];
    }
    ss += __shfl_xor(ss, 1);
    ss += __shfl_xor(ss, 2);
    float sc = 1.0f / fmaxf(sqrtf(ss), 1e-12f);
    unsigned short* dstk = (unsigned short*)(ws + (which ? OFF_XK : OFF_YK)) +
                           pair * 32768 + z0;
#pragma unroll
    for (int j = 0; j < 12; ++j) dstk[fidx(m, c0 + j)] = f2bf(v[j] * sc);
    if (q == 3) {
#pragma unroll
      for (int c = 48; c < 64; ++c) dstk[fidx(m, c)] = 0;
    }
  }
}

// ---- kernel 3: MFMA dist + softmax + plain-store slab colmax (UNCHANGED) --
__global__ __launch_bounds__(64, 2) void k_mm(float* __restrict__ ws) {
  int b = blockIdx.x;
  int pair = b >> 5, slab = b & 31;
  int lane = threadIdx.x;

  const unsigned short* xf =
      (const unsigned short*)(ws + OFF_XK) + pair * 32768;
  const unsigned short* yf =
      (const unsigned short*)(ws + OFF_YK) + pair * 32768;

  bf16x8 a0 = *(const bf16x8*)(xf + slab * 1024 + lane * 8);
  bf16x8 a1 = *(const bf16x8*)(xf + slab * 1024 + 512 + lane * 8);

  f32x4 d[32];
#pragma unroll
  for (int ct = 0; ct < 32; ++ct) {
    bf16x8 b0 = *(const bf16x8*)(yf + ct * 1024 + lane * 8);
    bf16x8 b1 = *(const bf16x8*)(yf + ct * 1024 + 512 + lane * 8);
    f32x4 z = {0.f, 0.f, 0.f, 0.f};
    f32x4 dd = __builtin_amdgcn_mfma_f32_16x16x32_bf16(a0, b0, z, 0, 0, 0);
    d[ct] = __builtin_amdgcn_mfma_f32_16x16x32_bf16(a1, b1, dd, 0, 0, 0);
  }

  float am0 = -3.4e38f, am1 = -3.4e38f, am2 = -3.4e38f, am3 = -3.4e38f;
#pragma unroll
  for (int ct = 0; ct < 32; ++ct) {
    am0 = fmaxf(am0, d[ct][0]); am1 = fmaxf(am1, d[ct][1]);
    am2 = fmaxf(am2, d[ct][2]); am3 = fmaxf(am3, d[ct][3]);
  }
#pragma unroll
  for (int off = 1; off < 16; off <<= 1) {
    am0 = fmaxf(am0, __shfl_xor(am0, off));
    am1 = fmaxf(am1, __shfl_xor(am1, off));
    am2 = fmaxf(am2, __shfl_xor(am2, off));
    am3 = fmaxf(am3, __shfl_xor(am3, off));
  }
  float inv0 = 2.f / ((1.f - am0) + 1e-5f), c20 = 2.f - inv0;
  float inv1 = 2.f / ((1.f - am1) + 1e-5f), c21 = 2.f - inv1;
  float inv2 = 2.f / ((1.f - am2) + 1e-5f), c22 = 2.f - inv2;
  float inv3 = 2.f / ((1.f - am3) + 1e-5f), c23 = 2.f - inv3;
  float sm0 = 0.f, sm1 = 0.f, sm2 = 0.f, sm3 = 0.f;
#pragma unroll
  for (int ct = 0; ct < 32; ++ct) {
    float e0 = __expf(fmaf(d[ct][0], inv0, c20));
    float e1 = __expf(fmaf(d[ct][1], inv1, c21));
    float e2 = __expf(fmaf(d[ct][2], inv2, c22));
    float e3 = __expf(fmaf(d[ct][3], inv3, c23));
    d[ct][0] = e0; d[ct][1] = e1; d[ct][2] = e2; d[ct][3] = e3;
    sm0 += e0; sm1 += e1; sm2 += e2; sm3 += e3;
  }
#pragma unroll
  for (int off = 1; off < 16; off <<= 1) {
    sm0 += __shfl_xor(sm0, off); sm1 += __shfl_xor(sm1, off);
    sm2 += __shfl_xor(sm2, off); sm3 += __shfl_xor(sm3, off);
  }
  float rs0 = 1.f / sm0, rs1 = 1.f / sm1, rs2 = 1.f / sm2, rs3 = 1.f / sm3;
  float* pm = ws + OFF_PM + (pair * 32 + slab) * M_;
#pragma unroll
  for (int ct = 0; ct < 32; ++ct) {
    float cc = fmaxf(fmaxf(d[ct][0] * rs0, d[ct][1] * rs1),
                     fmaxf(d[ct][2] * rs2, d[ct][3] * rs3));
    cc = fmaxf(cc, __shfl_xor(cc, 16));
    cc = fmaxf(cc, __shfl_xor(cc, 32));
    if (lane < 16) pm[ct * 16 + lane] = cc;
  }
}

// ---- kernel 4: colmax-combine + loss (xREPF diagnostic) -------------------
__global__ void k_final(float* __restrict__ ws, float* __restrict__ out) {
  int pair = blockIdx.x;
  int t = threadIdx.x, lane = t & 63, wv = t >> 6;
  __shared__ float red[4];
  __shared__ int lastflag;

  for (int rep = 0; rep < REPF; ++rep) {
    __syncthreads();                   // protect red/lastflag across reps
    int z0 = launder_zero();
    const float* pm = ws + OFF_PM + pair * 32 * M_ + z0;
    float m0 = 0.f, m1 = 0.f;
    for (int s = 0; s < 32; ++s) {
      m0 = fmaxf(m0, pm[s * M_ + t]);
      m1 = fmaxf(m1, pm[s * M_ + t + 256]);
    }
    float sum = m0 + m1;
#pragma unroll
    for (int off = 32; off; off >>= 1) sum += __shfl_xor(sum, off);
    if (lane == 0) red[wv] = sum;
    if (t == 0) lastflag = 0;
    __syncthreads();
    if (t == 0) {
      float tot = red[0] + red[1] + red[2] + red[3];
      float loss = -logf(tot * (1.0f / 512.0f) + 1e-5f);
      atomicExch((unsigned*)(ws + OFF_PL) + pair, __float_as_uint(loss));
      __threadfence();
      unsigned dct = atomicAdd((unsigned*)(ws + OFF_ALL), 1u);
      if (dct == PAIRS - 1) lastflag = 1;    // fires exactly once globally
    }
    __syncthreads();
    if (lastflag && t < 32) {
      float v = (t < PAIRS)
                    ? __uint_as_float(atomicOr((unsigned*)(ws + OFF_PL) + t, 0u))
                    : 0.f;
#pragma unroll
      for (int off = 16; off; off >>= 1) v += __shfl_xor(v, off);
      if (t == 0) out[0] = v * (1.0f / (float)PAIRS);
    }
  }
}

extern "C" void kernel_launch(void* const* d_in, const int* in_sizes, int n_in,
                              void* d_out, int out_size, void* d_ws, size_t ws_size,
                              hipStream_t stream) {
  const float* x = (const float*)d_in[0];
  const float* y = (const float*)d_in[1];
  const int* hi = (const int*)d_in[2];
  const int* wi = (const int*)d_in[3];
  const int* di = (const int*)d_in[4];
  float* ws = (float*)d_ws;
  float* out = (float*)d_out;

  k_gather<<<960, 256, 0, stream>>>(x, y, hi, wi, di, ws);
  k_nc<<<320, 256, 0, stream>>>(ws);
  k_mm<<<PAIRS * 32, 64, 0, stream>>>(ws);
  k_final<<<PAIRS, 256, 0, stream>>>(ws, out);
}

// Round 24
// 48.224 us; speedup vs baseline: 4.9070x; 4.9070x over previous
//
#include <hip/hip_runtime.h>
#include <hip/hip_bf16.h>
#include <math.h>

#define S_    10
#define C_    48
#define HWD   64
#define M_    512
#define PADK  4
#define PAIRS 20           // S_ * N(=2)

// ws layout (float offsets)
#define OFF_GY  0                         // raw y compact fp32, c-major
#define OFF_GX  491520                    // raw x compact fp32, c-major
#define OFF_MU  983040                    // 480 floats (channel MEANS)
#define OFF_CNT (OFF_MU + 480)            // 20 uint pair-arrival counters
#define OFF_ALL (OFF_CNT + 20)            // 1 uint pair-done counter
#define OFF_PL  (OFF_ALL + 1)             // 20 float pair losses
#define ZERO_N  (20 + 1 + 20)             // OFF_CNT..OFF_PL
// fragment-major bf16: per pair 32768 ushorts (64KB). 16B chunk = lane frag.
// ushort idx(m,c) = (m>>4)*1024 + (c>>5)*512 + ((c>>3)&3)*128 + (m&15)*8 + (c&7)
#define OFF_YK  983584
#define OFF_XK  (OFF_YK + 327680)
#define OFF_PM  (OFF_XK + 327680)         // [pair][slab][512] plain colmax

typedef __attribute__((ext_vector_type(8))) short bf16x8;
typedef __attribute__((ext_vector_type(4))) float f32x4;

__device__ __forceinline__ int gidx(int n, int c, int h, int w, int d) {
  return (((n * C_ + c) * HWD + h) * HWD + w) * HWD + d;
}

__device__ __forceinline__ unsigned short f2bf(float f) {  // RNE bf16
  unsigned u = __float_as_uint(f);
  u += 0x7FFFu + ((u >> 16) & 1u);
  return (unsigned short)(u >> 16);
}

__device__ __forceinline__ int fidx(int m, int c) {  // fragment-major ushort idx
  return ((m >> 4) << 10) + ((c >> 5) << 9) + (((c >> 3) & 3) << 7) +
         ((m & 15) << 3) + (c & 7);
}

// ---- kernel 1: gather x,y -> compact fp32; y means; zero final counters ---
__global__ void k_gather(const float* __restrict__ x, const float* __restrict__ y,
                         const int* __restrict__ hi, const int* __restrict__ wi,
                         const int* __restrict__ di, float* __restrict__ ws) {
  int b = blockIdx.x, t = threadIdx.x;
  int lane = t & 63, wv = t >> 6;
  __shared__ float red[4];
  if (b == 0 && t < ZERO_N) ws[OFF_CNT + t] = 0.f;   // zero CNT+ALL+PL
  int which = b >= 480;                              // 0 = y, 1 = x
  int r = which ? b - 480 : b;
  int s = r / C_, c = r % C_;
  const float* src = which ? x : y;
  int h0 = hi[s] - PADK, w0 = wi[s] - PADK, d0 = di[s] - PADK;
  float* dst = ws + (which ? OFF_GX : OFF_GY) + (s * 96 + 2 * c) * 512;
  float sum = 0.f;
#pragma unroll
  for (int j = 0; j < 4; ++j) {
    int i = t + 256 * j;
    int n = i >> 9, m = i & 511;
    float v = src[gidx(n, c, h0 + (m >> 6), w0 + ((m >> 3) & 7), d0 + (m & 7))];
    dst[n * 512 + m] = v;
    sum += v;
  }
  if (!which) {
#pragma unroll
    for (int off = 32; off; off >>= 1) sum += __shfl_xor(sum, off);
    if (lane == 0) red[wv] = sum;
    __syncthreads();
    if (t == 0)
      ws[OFF_MU + s * C_ + c] =
          (red[0] + red[1] + red[2] + red[3]) * (1.0f / 1024.0f);
  }
}

// ---- kernel 2: center + normalize -> bf16 FRAGMENT-MAJOR ------------------
__global__ void k_nc(float* __restrict__ ws) {
  int g = blockIdx.x * 256 + threadIdx.x;   // 0..81919
  int col = g >> 2;                         // 0..20479
  int q = threadIdx.x & 3;
  int which = col >= 10240;                 // 0 = y, 1 = x
  int cix = which ? col - 10240 : col;
  int pair = cix >> 9, m = cix & 511;
  int s = pair >> 1, n = pair & 1;
  const float* base = ws + (which ? OFF_GX : OFF_GY) + (s * 96 + n) * 512 + m;
  const float* mus = ws + OFF_MU + s * C_;
  int c0 = q * 12;
  float v[12], ss = 0.f;
#pragma unroll
  for (int j = 0; j < 12; ++j) {
    v[j] = base[(c0 + j) * 1024] - mus[c0 + j];
    ss += v[j] * v[j];
  }
  ss += __shfl_xor(ss, 1);
  ss += __shfl_xor(ss, 2);
  float sc = 1.0f / fmaxf(sqrtf(ss), 1e-12f);
  unsigned short* dstk = (unsigned short*)(ws + (which ? OFF_XK : OFF_YK)) +
                         pair * 32768;
#pragma unroll
  for (int j = 0; j < 12; ++j) dstk[fidx(m, c0 + j)] = f2bf(v[j] * sc);
  if (q == 3) {                         // zero pad k = 48..63
#pragma unroll
    for (int c = 48; c < 64; ++c) dstk[fidx(m, c)] = 0;
  }
}

// ---- kernel 3: MFMA dist + softmax + plain-store slab colmax + fused final
// 640 blocks x 64 thr; block = (pair, 16-row slab). Per-element colmax stays
// PLAIN stores (the R16-R21 17us tail was 512 contended device atomics/block);
// only a 1-atomic arrival counter remains. 32nd block per pair reduces pm
// with plain coalesced loads after a device-scope acquire fence.
__global__ __launch_bounds__(64, 2) void k_mm(float* __restrict__ ws,
                                              float* __restrict__ out) {
  int b = blockIdx.x;
  int pair = b >> 5, slab = b & 31;
  int lane = threadIdx.x;
  __shared__ unsigned arr;
  __shared__ int lastflag;

  const unsigned short* xf =
      (const unsigned short*)(ws + OFF_XK) + pair * 32768;
  const unsigned short* yf =
      (const unsigned short*)(ws + OFF_YK) + pair * 32768;

  // A-frags: slab chunk, khalf 0/1 — coalesced 1KB loads
  bf16x8 a0 = *(const bf16x8*)(xf + slab * 1024 + lane * 8);
  bf16x8 a1 = *(const bf16x8*)(xf + slab * 1024 + 512 + lane * 8);

  f32x4 d[32];
#pragma unroll
  for (int ct = 0; ct < 32; ++ct) {    // 64 coalesced 1KB loads, independent
    bf16x8 b0 = *(const bf16x8*)(yf + ct * 1024 + lane * 8);
    bf16x8 b1 = *(const bf16x8*)(yf + ct * 1024 + 512 + lane * 8);
    f32x4 z = {0.f, 0.f, 0.f, 0.f};
    f32x4 dd = __builtin_amdgcn_mfma_f32_16x16x32_bf16(a0, b0, z, 0, 0, 0);
    d[ct] = __builtin_amdgcn_mfma_f32_16x16x32_bf16(a1, b1, dd, 0, 0, 0);
  }

  // epilogue: amax per row (dmin = 1 - amax) -> softmax -> slab colmax
  float am0 = -3.4e38f, am1 = -3.4e38f, am2 = -3.4e38f, am3 = -3.4e38f;
#pragma unroll
  for (int ct = 0; ct < 32; ++ct) {
    am0 = fmaxf(am0, d[ct][0]); am1 = fmaxf(am1, d[ct][1]);
    am2 = fmaxf(am2, d[ct][2]); am3 = fmaxf(am3, d[ct][3]);
  }
#pragma unroll
  for (int off = 1; off < 16; off <<= 1) {
    am0 = fmaxf(am0, __shfl_xor(am0, off));
    am1 = fmaxf(am1, __shfl_xor(am1, off));
    am2 = fmaxf(am2, __shfl_xor(am2, off));
    am3 = fmaxf(am3, __shfl_xor(am3, off));
  }
  float inv0 = 2.f / ((1.f - am0) + 1e-5f), c20 = 2.f - inv0;
  float inv1 = 2.f / ((1.f - am1) + 1e-5f), c21 = 2.f - inv1;
  float inv2 = 2.f / ((1.f - am2) + 1e-5f), c22 = 2.f - inv2;
  float inv3 = 2.f / ((1.f - am3) + 1e-5f), c23 = 2.f - inv3;
  float sm0 = 0.f, sm1 = 0.f, sm2 = 0.f, sm3 = 0.f;
#pragma unroll
  for (int ct = 0; ct < 32; ++ct) {    // logit = 2 - (1-a)*inv = c2 + a*inv
    float e0 = __expf(fmaf(d[ct][0], inv0, c20));
    float e1 = __expf(fmaf(d[ct][1], inv1, c21));
    float e2 = __expf(fmaf(d[ct][2], inv2, c22));
    float e3 = __expf(fmaf(d[ct][3], inv3, c23));
    d[ct][0] = e0; d[ct][1] = e1; d[ct][2] = e2; d[ct][3] = e3;
    sm0 += e0; sm1 += e1; sm2 += e2; sm3 += e3;
  }
#pragma unroll
  for (int off = 1; off < 16; off <<= 1) {
    sm0 += __shfl_xor(sm0, off); sm1 += __shfl_xor(sm1, off);
    sm2 += __shfl_xor(sm2, off); sm3 += __shfl_xor(sm3, off);
  }
  float rs0 = 1.f / sm0, rs1 = 1.f / sm1, rs2 = 1.f / sm2, rs3 = 1.f / sm3;
  float* pm = ws + OFF_PM + (pair * 32 + slab) * M_;
#pragma unroll
  for (int ct = 0; ct < 32; ++ct) {
    float cc = fmaxf(fmaxf(d[ct][0] * rs0, d[ct][1] * rs1),
                     fmaxf(d[ct][2] * rs2, d[ct][3] * rs3));
    cc = fmaxf(cc, __shfl_xor(cc, 16));
    cc = fmaxf(cc, __shfl_xor(cc, 32));  // max over this slab's 16 rows
    if (lane < 16) pm[ct * 16 + lane] = cc;   // plain coalesced store
  }

  // ---- fused final: arrival counter; 32nd block per pair reduces ---------
  __threadfence();                     // release: pm stores visible at device
  if (lane == 0) arr = atomicAdd((unsigned*)(ws + OFF_CNT) + pair, 1u);
  __syncthreads();
  if (arr == 31) {
    __threadfence();                   // acquire after counter observation
    const float* pmp = ws + OFF_PM + pair * 32 * M_;
    float4 mA = {0.f, 0.f, 0.f, 0.f}, mB = {0.f, 0.f, 0.f, 0.f};
    for (int s2 = 0; s2 < 32; ++s2) {  // plain coalesced: 2KB/slab across wave
      float4 vA = *(const float4*)(pmp + s2 * M_ + lane * 8);
      float4 vB = *(const float4*)(pmp + s2 * M_ + lane * 8 + 4);
      mA.x = fmaxf(mA.x, vA.x); mA.y = fmaxf(mA.y, vA.y);
      mA.z = fmaxf(mA.z, vA.z); mA.w = fmaxf(mA.w, vA.w);
      mB.x = fmaxf(mB.x, vB.x); mB.y = fmaxf(mB.y, vB.y);
      mB.z = fmaxf(mB.z, vB.z); mB.w = fmaxf(mB.w, vB.w);
    }
    float sum = ((mA.x + mA.y) + (mA.z + mA.w)) +
                ((mB.x + mB.y) + (mB.z + mB.w));
#pragma unroll
    for (int off = 32; off; off >>= 1) sum += __shfl_xor(sum, off);
    if (lane == 0) {
      lastflag = 0;
      float loss = -logf(sum * (1.0f / 512.0f) + 1e-5f);
      atomicExch((unsigned*)(ws + OFF_PL) + pair, __float_as_uint(loss));
      __threadfence();
      unsigned dct = atomicAdd((unsigned*)(ws + OFF_ALL), 1u);
      if (dct == PAIRS - 1) lastflag = 1;
    }
    __syncthreads();
    if (lastflag && lane < 32) {       // parallel 20-loss readback
      float v = (lane < PAIRS)
                    ? __uint_as_float(atomicOr((unsigned*)(ws + OFF_PL) + lane, 0u))
                    : 0.f;
#pragma unroll
      for (int off = 16; off; off >>= 1) v += __shfl_xor(v, off);
      if (lane == 0) out[0] = v * (1.0f / (float)PAIRS);
    }
  }
}

extern "C" void kernel_launch(void* const* d_in, const int* in_sizes, int n_in,
                              void* d_out, int out_size, void* d_ws, size_t ws_size,
                              hipStream_t stream) {
  const float* x = (const float*)d_in[0];
  const float* y = (const float*)d_in[1];
  const int* hi = (const int*)d_in[2];
  const int* wi = (const int*)d_in[3];
  const int* di = (const int*)d_in[4];
  float* ws = (float*)d_ws;
  float* out = (float*)d_out;

  k_gather<<<960, 256, 0, stream>>>(x, y, hi, wi, di, ws);
  k_nc<<<320, 256, 0, stream>>>(ws);
  k_mm<<<PAIRS * 32, 64, 0, stream>>>(ws, out);
}

// Round 25
// 37.802 us; speedup vs baseline: 6.2598x; 1.2757x over previous
//
#include <hip/hip_runtime.h>
#include <hip/hip_bf16.h>
#include <math.h>

#define S_    10
#define C_    48
#define HWD   64
#define M_    512
#define PADK  4
#define PAIRS 20           // S_ * N(=2)

// ws layout (float offsets)
#define OFF_GY  0                         // raw y compact fp32, c-major
#define OFF_GX  491520                    // raw x compact fp32, c-major
#define OFF_MU  983040                    // 480 floats (channel MEANS)
#define OFF_CNT (OFF_MU + 480)            // 20 uint pair-arrival counters
#define OFF_ALL (OFF_CNT + 20)            // 1 uint pair-done counter
#define OFF_PL  (OFF_ALL + 1)             // 20 float pair losses
#define ZERO_N  (20 + 1 + 20)             // OFF_CNT..OFF_PL
// fragment-major bf16: per pair 32768 ushorts (64KB). 16B chunk = lane frag.
// ushort idx(m,c) = (m>>4)*1024 + (c>>5)*512 + ((c>>3)&3)*128 + (m&15)*8 + (c&7)
#define OFF_YK  983584
#define OFF_XK  (OFF_YK + 327680)
#define OFF_PM  (OFF_XK + 327680)         // [pair][slab][512] colmax (atomicExch)

typedef __attribute__((ext_vector_type(8))) short bf16x8;
typedef __attribute__((ext_vector_type(4))) float f32x4;

__device__ __forceinline__ int gidx(int n, int c, int h, int w, int d) {
  return (((n * C_ + c) * HWD + h) * HWD + w) * HWD + d;
}

__device__ __forceinline__ unsigned short f2bf(float f) {  // RNE bf16
  unsigned u = __float_as_uint(f);
  u += 0x7FFFu + ((u >> 16) & 1u);
  return (unsigned short)(u >> 16);
}

__device__ __forceinline__ int fidx(int m, int c) {  // fragment-major ushort idx
  return ((m >> 4) << 10) + ((c >> 5) << 9) + (((c >> 3) & 3) << 7) +
         ((m & 15) << 3) + (c & 7);
}

// ---- kernel 1: gather x,y -> compact fp32; y means; zero final counters ---
__global__ void k_gather(const float* __restrict__ x, const float* __restrict__ y,
                         const int* __restrict__ hi, const int* __restrict__ wi,
                         const int* __restrict__ di, float* __restrict__ ws) {
  int b = blockIdx.x, t = threadIdx.x;
  int lane = t & 63, wv = t >> 6;
  __shared__ float red[4];
  if (b == 0 && t < ZERO_N) ws[OFF_CNT + t] = 0.f;   // zero CNT+ALL+PL
  int which = b >= 480;                              // 0 = y, 1 = x
  int r = which ? b - 480 : b;
  int s = r / C_, c = r % C_;
  const float* src = which ? x : y;
  int h0 = hi[s] - PADK, w0 = wi[s] - PADK, d0 = di[s] - PADK;
  float* dst = ws + (which ? OFF_GX : OFF_GY) + (s * 96 + 2 * c) * 512;
  float sum = 0.f;
#pragma unroll
  for (int j = 0; j < 4; ++j) {
    int i = t + 256 * j;
    int n = i >> 9, m = i & 511;
    float v = src[gidx(n, c, h0 + (m >> 6), w0 + ((m >> 3) & 7), d0 + (m & 7))];
    dst[n * 512 + m] = v;
    sum += v;
  }
  if (!which) {
#pragma unroll
    for (int off = 32; off; off >>= 1) sum += __shfl_xor(sum, off);
    if (lane == 0) red[wv] = sum;
    __syncthreads();
    if (t == 0)
      ws[OFF_MU + s * C_ + c] =
          (red[0] + red[1] + red[2] + red[3]) * (1.0f / 1024.0f);
  }
}

// ---- kernel 2: center + normalize -> bf16 FRAGMENT-MAJOR ------------------
__global__ void k_nc(float* __restrict__ ws) {
  int g = blockIdx.x * 256 + threadIdx.x;   // 0..81919
  int col = g >> 2;                         // 0..20479
  int q = threadIdx.x & 3;
  int which = col >= 10240;                 // 0 = y, 1 = x
  int cix = which ? col - 10240 : col;
  int pair = cix >> 9, m = cix & 511;
  int s = pair >> 1, n = pair & 1;
  const float* base = ws + (which ? OFF_GX : OFF_GY) + (s * 96 + n) * 512 + m;
  const float* mus = ws + OFF_MU + s * C_;
  int c0 = q * 12;
  float v[12], ss = 0.f;
#pragma unroll
  for (int j = 0; j < 12; ++j) {
    v[j] = base[(c0 + j) * 1024] - mus[c0 + j];
    ss += v[j] * v[j];
  }
  ss += __shfl_xor(ss, 1);
  ss += __shfl_xor(ss, 2);
  float sc = 1.0f / fmaxf(sqrtf(ss), 1e-12f);
  unsigned short* dstk = (unsigned short*)(ws + (which ? OFF_XK : OFF_YK)) +
                         pair * 32768;
#pragma unroll
  for (int j = 0; j < 12; ++j) dstk[fidx(m, c0 + j)] = f2bf(v[j] * sc);
  if (q == 3) {                         // zero pad k = 48..63
#pragma unroll
    for (int c = 48; c < 64; ++c) dstk[fidx(m, c)] = 0;
  }
}

// ---- kernel 3: MFMA dist + softmax + atomicExch colmax + fence-free final
// 640 blocks x 64 thr; block = (pair, 16-row slab). pm written via
// UNCONTENDED atomicExch (LLC-coherent, fire-and-forget — no wbl2 fence);
// s_waitcnt vmcnt(0) before the 1-atomic arrival counter guarantees
// completion; 32nd block reduces pm with plain coalesced loads (its L2
// cannot hold stale pm: kernel-start invalidate + nobody read pm earlier).
__global__ __launch_bounds__(64, 2) void k_mm(float* __restrict__ ws,
                                              float* __restrict__ out) {
  int b = blockIdx.x;
  int pair = b >> 5, slab = b & 31;
  int lane = threadIdx.x;
  __shared__ unsigned arr;
  __shared__ int lastflag;

  const unsigned short* xf =
      (const unsigned short*)(ws + OFF_XK) + pair * 32768;
  const unsigned short* yf =
      (const unsigned short*)(ws + OFF_YK) + pair * 32768;

  bf16x8 a0 = *(const bf16x8*)(xf + slab * 1024 + lane * 8);
  bf16x8 a1 = *(const bf16x8*)(xf + slab * 1024 + 512 + lane * 8);

  f32x4 d[32];
#pragma unroll
  for (int ct = 0; ct < 32; ++ct) {    // 64 coalesced 1KB loads, independent
    bf16x8 b0 = *(const bf16x8*)(yf + ct * 1024 + lane * 8);
    bf16x8 b1 = *(const bf16x8*)(yf + ct * 1024 + 512 + lane * 8);
    f32x4 z = {0.f, 0.f, 0.f, 0.f};
    f32x4 dd = __builtin_amdgcn_mfma_f32_16x16x32_bf16(a0, b0, z, 0, 0, 0);
    d[ct] = __builtin_amdgcn_mfma_f32_16x16x32_bf16(a1, b1, dd, 0, 0, 0);
  }

  // epilogue: amax per row (dmin = 1 - amax) -> softmax -> slab colmax
  float am0 = -3.4e38f, am1 = -3.4e38f, am2 = -3.4e38f, am3 = -3.4e38f;
#pragma unroll
  for (int ct = 0; ct < 32; ++ct) {
    am0 = fmaxf(am0, d[ct][0]); am1 = fmaxf(am1, d[ct][1]);
    am2 = fmaxf(am2, d[ct][2]); am3 = fmaxf(am3, d[ct][3]);
  }
#pragma unroll
  for (int off = 1; off < 16; off <<= 1) {
    am0 = fmaxf(am0, __shfl_xor(am0, off));
    am1 = fmaxf(am1, __shfl_xor(am1, off));
    am2 = fmaxf(am2, __shfl_xor(am2, off));
    am3 = fmaxf(am3, __shfl_xor(am3, off));
  }
  float inv0 = 2.f / ((1.f - am0) + 1e-5f), c20 = 2.f - inv0;
  float inv1 = 2.f / ((1.f - am1) + 1e-5f), c21 = 2.f - inv1;
  float inv2 = 2.f / ((1.f - am2) + 1e-5f), c22 = 2.f - inv2;
  float inv3 = 2.f / ((1.f - am3) + 1e-5f), c23 = 2.f - inv3;
  float sm0 = 0.f, sm1 = 0.f, sm2 = 0.f, sm3 = 0.f;
#pragma unroll
  for (int ct = 0; ct < 32; ++ct) {    // logit = 2 - (1-a)*inv = c2 + a*inv
    float e0 = __expf(fmaf(d[ct][0], inv0, c20));
    float e1 = __expf(fmaf(d[ct][1], inv1, c21));
    float e2 = __expf(fmaf(d[ct][2], inv2, c22));
    float e3 = __expf(fmaf(d[ct][3], inv3, c23));
    d[ct][0] = e0; d[ct][1] = e1; d[ct][2] = e2; d[ct][3] = e3;
    sm0 += e0; sm1 += e1; sm2 += e2; sm3 += e3;
  }
#pragma unroll
  for (int off = 1; off < 16; off <<= 1) {
    sm0 += __shfl_xor(sm0, off); sm1 += __shfl_xor(sm1, off);
    sm2 += __shfl_xor(sm2, off); sm3 += __shfl_xor(sm3, off);
  }
  float rs0 = 1.f / sm0, rs1 = 1.f / sm1, rs2 = 1.f / sm2, rs3 = 1.f / sm3;
  unsigned* pm = (unsigned*)(ws + OFF_PM) + (pair * 32 + slab) * M_;
#pragma unroll
  for (int ct = 0; ct < 32; ++ct) {
    float cc = fmaxf(fmaxf(d[ct][0] * rs0, d[ct][1] * rs1),
                     fmaxf(d[ct][2] * rs2, d[ct][3] * rs3));
    cc = fmaxf(cc, __shfl_xor(cc, 16));
    cc = fmaxf(cc, __shfl_xor(cc, 32));  // max over this slab's 16 rows
    if (lane < 16)                        // uncontended LLC-coherent write
      atomicExch(&pm[ct * 16 + lane], __float_as_uint(cc));
  }

  // wait own exchanges complete at the coherence point (no L2 writeback)
  asm volatile("s_waitcnt vmcnt(0)" ::: "memory");
  if (lane == 0) arr = atomicAdd((unsigned*)(ws + OFF_CNT) + pair, 1u);
  __syncthreads();
  if (arr == 31) {                     // last block: plain coalesced reduce
    const float* pmp = ws + OFF_PM + pair * 32 * M_;
    float4 mA = {0.f, 0.f, 0.f, 0.f}, mB = {0.f, 0.f, 0.f, 0.f};
    for (int s2 = 0; s2 < 32; ++s2) {
      float4 vA = *(const float4*)(pmp + s2 * M_ + lane * 8);
      float4 vB = *(const float4*)(pmp + s2 * M_ + lane * 8 + 4);
      mA.x = fmaxf(mA.x, vA.x); mA.y = fmaxf(mA.y, vA.y);
      mA.z = fmaxf(mA.z, vA.z); mA.w = fmaxf(mA.w, vA.w);
      mB.x = fmaxf(mB.x, vB.x); mB.y = fmaxf(mB.y, vB.y);
      mB.z = fmaxf(mB.z, vB.z); mB.w = fmaxf(mB.w, vB.w);
    }
    float sum = ((mA.x + mA.y) + (mA.z + mA.w)) +
                ((mB.x + mB.y) + (mB.z + mB.w));
#pragma unroll
    for (int off = 32; off; off >>= 1) sum += __shfl_xor(sum, off);
    if (lane == 0) {
      lastflag = 0;
      float loss = -logf(sum * (1.0f / 512.0f) + 1e-5f);
      atomicExch((unsigned*)(ws + OFF_PL) + pair, __float_as_uint(loss));
      __threadfence();
      unsigned dct = atomicAdd((unsigned*)(ws + OFF_ALL), 1u);
      if (dct == PAIRS - 1) lastflag = 1;
    }
    __syncthreads();
    if (lastflag && lane < 32) {       // parallel 20-loss readback
      float v = (lane < PAIRS)
                    ? __uint_as_float(atomicOr((unsigned*)(ws + OFF_PL) + lane, 0u))
                    : 0.f;
#pragma unroll
      for (int off = 16; off; off >>= 1) v += __shfl_xor(v, off);
      if (lane == 0) out[0] = v * (1.0f / (float)PAIRS);
    }
  }
}

extern "C" void kernel_launch(void* const* d_in, const int* in_sizes, int n_in,
                              void* d_out, int out_size, void* d_ws, size_t ws_size,
                              hipStream_t stream) {
  const float* x = (const float*)d_in[0];
  const float* y = (const float*)d_in[1];
  const int* hi = (const int*)d_in[2];
  const int* wi = (const int*)d_in[3];
  const int* di = (const int*)d_in[4];
  float* ws = (float*)d_ws;
  float* out = (float*)d_out;

  k_gather<<<960, 256, 0, stream>>>(x, y, hi, wi, di, ws);
  k_nc<<<320, 256, 0, stream>>>(ws);
  k_mm<<<PAIRS * 32, 64, 0, stream>>>(ws, out);
}

// Round 26
// 33.211 us; speedup vs baseline: 7.1251x; 1.1382x over previous
//
#include <hip/hip_runtime.h>
#include <hip/hip_bf16.h>
#include <math.h>

#define S_    10
#define C_    48
#define HWD   64
#define M_    512
#define PADK  4
#define PAIRS 20           // S_ * N(=2)
#define CSTRIDE (HWD * HWD * HWD)

// ws layout (float offsets)
#define OFF_GY  0                         // raw y compact fp32, c-major (491520)
#define OFF_MU  491520                    // 480 floats (channel MEANS)
#define OFF_CNT (OFF_MU + 480)            // 20 uint pair-arrival counters
#define OFF_ALL (OFF_CNT + 20)            // 1 uint pair-done counter
#define OFF_PL  (OFF_ALL + 1)             // 20 float pair losses
#define ZERO_N  (20 + 1 + 20)
// fragment-major bf16 y: per pair 32768 ushorts (64KB). 16B chunk = lane frag.
// ushort idx(m,c) = (m>>4)*1024 + (c>>5)*512 + ((c>>3)&3)*128 + (m&15)*8 + (c&7)
#define OFF_YK  492032                    // 20*32768 ushorts = 327680 floats
#define OFF_PM  (OFF_YK + 327680)         // [pair][slab][512] plain colmax

typedef __attribute__((ext_vector_type(8))) short bf16x8;
typedef __attribute__((ext_vector_type(4))) float f32x4;

__device__ __forceinline__ int gidx(int n, int c, int h, int w, int d) {
  return (((n * C_ + c) * HWD + h) * HWD + w) * HWD + d;
}

__device__ __forceinline__ unsigned short f2bf(float f) {  // RNE bf16
  unsigned u = __float_as_uint(f);
  u += 0x7FFFu + ((u >> 16) & 1u);
  return (unsigned short)(u >> 16);
}

__device__ __forceinline__ int fidx(int m, int c) {  // fragment-major ushort idx
  return ((m >> 4) << 10) + ((c >> 5) << 9) + (((c >> 3) & 3) << 7) +
         ((m & 15) << 3) + (c & 7);
}

// ---- kernel 1: gather Y ONLY -> compact fp32; y means; zero counters ------
// 480 blocks x 256 thr; block = (s,c). x never touches ws (gathered in k_mm).
__global__ void k_gather(const float* __restrict__ y, const int* __restrict__ hi,
                         const int* __restrict__ wi, const int* __restrict__ di,
                         float* __restrict__ ws) {
  int b = blockIdx.x, t = threadIdx.x;
  int lane = t & 63, wv = t >> 6;
  __shared__ float red[4];
  if (b == 0 && t < ZERO_N) ws[OFF_CNT + t] = 0.f;   // zero CNT+ALL+PL
  int s = b / C_, c = b % C_;
  int h0 = hi[s] - PADK, w0 = wi[s] - PADK, d0 = di[s] - PADK;
  float* dst = ws + OFF_GY + (s * 96 + 2 * c) * 512;
  float sum = 0.f;
#pragma unroll
  for (int j = 0; j < 4; ++j) {
    int i = t + 256 * j;
    int n = i >> 9, m = i & 511;
    float v = y[gidx(n, c, h0 + (m >> 6), w0 + ((m >> 3) & 7), d0 + (m & 7))];
    dst[n * 512 + m] = v;
    sum += v;
  }
#pragma unroll
  for (int off = 32; off; off >>= 1) sum += __shfl_xor(sum, off);
  if (lane == 0) red[wv] = sum;
  __syncthreads();
  if (t == 0)
    ws[OFF_MU + s * C_ + c] =
        (red[0] + red[1] + red[2] + red[3]) * (1.0f / 1024.0f);
}

// ---- kernel 2: center + normalize Y -> bf16 FRAGMENT-MAJOR ----------------
// 160 blocks x 256 thr; 4 lanes per column (12 channels each).
__global__ void k_nc(float* __restrict__ ws) {
  int g = blockIdx.x * 256 + threadIdx.x;   // 0..40959
  int col = g >> 2;                         // 0..10239
  int q = threadIdx.x & 3;
  int pair = col >> 9, m = col & 511;
  int s = pair >> 1, n = pair & 1;
  const float* base = ws + OFF_GY + (s * 96 + n) * 512 + m;
  const float* mus = ws + OFF_MU + s * C_;
  int c0 = q * 12;
  float v[12], ss = 0.f;
#pragma unroll
  for (int j = 0; j < 12; ++j) {
    v[j] = base[(c0 + j) * 1024] - mus[c0 + j];
    ss += v[j] * v[j];
  }
  ss += __shfl_xor(ss, 1);
  ss += __shfl_xor(ss, 2);
  float sc = 1.0f / fmaxf(sqrtf(ss), 1e-12f);
  unsigned short* dstk = (unsigned short*)(ws + OFF_YK) + pair * 32768;
#pragma unroll
  for (int j = 0; j < 12; ++j) dstk[fidx(m, c0 + j)] = f2bf(v[j] * sc);
  if (q == 3) {                         // zero pad k = 48..63
#pragma unroll
    for (int c = 48; c < 64; ++c) dstk[fidx(m, c)] = 0;
  }
}

// ---- kernel 3: inline x-gather+norm (A-frags in-register) + MFMA dist +
//      softmax + plain-store slab colmax. 640 blocks x 64 thr, no LDS/barrier.
// A-frag lane map (matches YK/B layout, m89-verified): row16 = lane&15,
// kg = lane>>4; a0 = channels kg*8..+7, a1 = 32+kg*8..+7 (>=48 -> 0).
// Column norm: lanes {kg=0..3} of a row partition channels; 2 shfl_xor.
__global__ __launch_bounds__(64, 2) void k_mm(const float* __restrict__ x,
                                              const int* __restrict__ hi,
                                              const int* __restrict__ wi,
                                              const int* __restrict__ di,
                                              float* __restrict__ ws) {
  int b = blockIdx.x;
  int pair = b >> 5, slab = b & 31;
  int s = pair >> 1, n = pair & 1;
  int lane = threadIdx.x;
  int r16 = lane & 15, kg = lane >> 4;

  // ---- build A-frags from raw x (cold loads hide under B/MFMA of peers) --
  int h0 = hi[s] - PADK, w0 = wi[s] - PADK, d0 = di[s] - PADK;
  int m = slab * 16 + r16;
  int xb = gidx(n, 0, h0 + (m >> 6), w0 + ((m >> 3) & 7), d0 + (m & 7));
  const float* mus = ws + OFF_MU + s * C_;
  int c0 = kg * 8, c1 = 32 + kg * 8;
  float v0[8], v1[8], ss = 0.f;
#pragma unroll
  for (int j = 0; j < 8; ++j) {
    v0[j] = x[xb + (c0 + j) * CSTRIDE] - mus[c0 + j];
    ss += v0[j] * v0[j];
  }
  if (kg < 2) {
#pragma unroll
    for (int j = 0; j < 8; ++j) {
      v1[j] = x[xb + (c1 + j) * CSTRIDE] - mus[c1 + j];
      ss += v1[j] * v1[j];
    }
  } else {
#pragma unroll
    for (int j = 0; j < 8; ++j) v1[j] = 0.f;
  }
  ss += __shfl_xor(ss, 16);            // combine kg 0<->1, 2<->3
  ss += __shfl_xor(ss, 32);            // combine kg {0,1}<->{2,3}
  float sc = 1.0f / fmaxf(sqrtf(ss), 1e-12f);
  bf16x8 a0, a1;
#pragma unroll
  for (int j = 0; j < 8; ++j) {
    a0[j] = (short)f2bf(v0[j] * sc);
    a1[j] = (short)f2bf(v1[j] * sc);
  }

  // ---- B from YK (coalesced 1KB), 32 MFMA-tile pairs ---------------------
  const unsigned short* yf = (const unsigned short*)(ws + OFF_YK) + pair * 32768;
  f32x4 d[32];
#pragma unroll
  for (int ct = 0; ct < 32; ++ct) {
    bf16x8 b0 = *(const bf16x8*)(yf + ct * 1024 + lane * 8);
    bf16x8 b1 = *(const bf16x8*)(yf + ct * 1024 + 512 + lane * 8);
    f32x4 z = {0.f, 0.f, 0.f, 0.f};
    f32x4 dd = __builtin_amdgcn_mfma_f32_16x16x32_bf16(a0, b0, z, 0, 0, 0);
    d[ct] = __builtin_amdgcn_mfma_f32_16x16x32_bf16(a1, b1, dd, 0, 0, 0);
  }

  // epilogue: amax per row (dmin = 1 - amax) -> softmax -> slab colmax
  float am0 = -3.4e38f, am1 = -3.4e38f, am2 = -3.4e38f, am3 = -3.4e38f;
#pragma unroll
  for (int ct = 0; ct < 32; ++ct) {
    am0 = fmaxf(am0, d[ct][0]); am1 = fmaxf(am1, d[ct][1]);
    am2 = fmaxf(am2, d[ct][2]); am3 = fmaxf(am3, d[ct][3]);
  }
#pragma unroll
  for (int off = 1; off < 16; off <<= 1) {
    am0 = fmaxf(am0, __shfl_xor(am0, off));
    am1 = fmaxf(am1, __shfl_xor(am1, off));
    am2 = fmaxf(am2, __shfl_xor(am2, off));
    am3 = fmaxf(am3, __shfl_xor(am3, off));
  }
  float inv0 = 2.f / ((1.f - am0) + 1e-5f), c20 = 2.f - inv0;
  float inv1 = 2.f / ((1.f - am1) + 1e-5f), c21 = 2.f - inv1;
  float inv2 = 2.f / ((1.f - am2) + 1e-5f), c22 = 2.f - inv2;
  float inv3 = 2.f / ((1.f - am3) + 1e-5f), c23 = 2.f - inv3;
  float sm0 = 0.f, sm1 = 0.f, sm2 = 0.f, sm3 = 0.f;
#pragma unroll
  for (int ct = 0; ct < 32; ++ct) {    // logit = 2 - (1-a)*inv = c2 + a*inv
    float e0 = __expf(fmaf(d[ct][0], inv0, c20));
    float e1 = __expf(fmaf(d[ct][1], inv1, c21));
    float e2 = __expf(fmaf(d[ct][2], inv2, c22));
    float e3 = __expf(fmaf(d[ct][3], inv3, c23));
    d[ct][0] = e0; d[ct][1] = e1; d[ct][2] = e2; d[ct][3] = e3;
    sm0 += e0; sm1 += e1; sm2 += e2; sm3 += e3;
  }
#pragma unroll
  for (int off = 1; off < 16; off <<= 1) {
    sm0 += __shfl_xor(sm0, off); sm1 += __shfl_xor(sm1, off);
    sm2 += __shfl_xor(sm2, off); sm3 += __shfl_xor(sm3, off);
  }
  float rs0 = 1.f / sm0, rs1 = 1.f / sm1, rs2 = 1.f / sm2, rs3 = 1.f / sm3;
  float* pm = ws + OFF_PM + (pair * 32 + slab) * M_;
#pragma unroll
  for (int ct = 0; ct < 32; ++ct) {
    float cc = fmaxf(fmaxf(d[ct][0] * rs0, d[ct][1] * rs1),
                     fmaxf(d[ct][2] * rs2, d[ct][3] * rs3));
    cc = fmaxf(cc, __shfl_xor(cc, 16));
    cc = fmaxf(cc, __shfl_xor(cc, 32));  // max over this slab's 16 rows
    if (lane < 16) pm[ct * 16 + lane] = cc;   // plain coalesced store
  }
}

// ---- kernel 4: per-pair colmax-combine + loss; last pair writes out -------
// 20 blocks x 256 thr; kernel boundary = coherence for pm (R22-proven).
__global__ void k_final(float* __restrict__ ws, float* __restrict__ out) {
  int pair = blockIdx.x;
  int t = threadIdx.x, lane = t & 63, wv = t >> 6;
  __shared__ float red[4];
  __shared__ int lastflag;
  const float* pm = ws + OFF_PM + pair * 32 * M_;

  float m0 = 0.f, m1 = 0.f;
  for (int s2 = 0; s2 < 32; ++s2) {
    m0 = fmaxf(m0, pm[s2 * M_ + t]);
    m1 = fmaxf(m1, pm[s2 * M_ + t + 256]);
  }
  float sum = m0 + m1;
#pragma unroll
  for (int off = 32; off; off >>= 1) sum += __shfl_xor(sum, off);
  if (lane == 0) red[wv] = sum;
  if (t == 0) lastflag = 0;
  __syncthreads();
  if (t == 0) {
    float tot = red[0] + red[1] + red[2] + red[3];
    float loss = -logf(tot * (1.0f / 512.0f) + 1e-5f);
    atomicExch((unsigned*)(ws + OFF_PL) + pair, __float_as_uint(loss));
    __threadfence();
    unsigned dct = atomicAdd((unsigned*)(ws + OFF_ALL), 1u);
    if (dct == PAIRS - 1) lastflag = 1;
  }
  __syncthreads();
  if (lastflag && t < 32) {            // parallel 20-loss readback
    float v = (t < PAIRS)
                  ? __uint_as_float(atomicOr((unsigned*)(ws + OFF_PL) + t, 0u))
                  : 0.f;
#pragma unroll
    for (int off = 16; off; off >>= 1) v += __shfl_xor(v, off);
    if (t == 0) out[0] = v * (1.0f / (float)PAIRS);
  }
}

extern "C" void kernel_launch(void* const* d_in, const int* in_sizes, int n_in,
                              void* d_out, int out_size, void* d_ws, size_t ws_size,
                              hipStream_t stream) {
  const float* x = (const float*)d_in[0];
  const float* y = (const float*)d_in[1];
  const int* hi = (const int*)d_in[2];
  const int* wi = (const int*)d_in[3];
  const int* di = (const int*)d_in[4];
  float* ws = (float*)d_ws;
  float* out = (float*)d_out;

  k_gather<<<S_ * C_, 256, 0, stream>>>(y, hi, wi, di, ws);
  k_nc<<<160, 256, 0, stream>>>(ws);
  k_mm<<<PAIRS * 32, 64, 0, stream>>>(x, hi, wi, di, ws);
  k_final<<<PAIRS, 256, 0, stream>>>(ws, out);
}

// Round 27
// 32.304 us; speedup vs baseline: 7.3252x; 1.0281x over previous
//
#include <hip/hip_runtime.h>
#include <hip/hip_bf16.h>
#include <math.h>

#define S_    10
#define C_    48
#define HWD   64
#define M_    512
#define PADK  4
#define PAIRS 20           // S_ * N(=2)

// ws layout (float offsets)
#define OFF_GY  0                         // raw y compact fp32, c-major
#define OFF_GX  491520                    // raw x compact fp32, c-major
#define OFF_MU  983040                    // 480 floats (channel MEANS)
#define OFF_CNT (OFF_MU + 480)            // 20 uint pair-arrival counters (k_final)
#define OFF_ALL (OFF_CNT + 20)            // 1 uint pair-done counter
#define OFF_PL  (OFF_ALL + 1)             // 20 float pair losses
#define ZERO_N  (20 + 1 + 20)             // OFF_CNT..OFF_PL
// fragment-major bf16: per pair 32768 ushorts (64KB). 16B chunk = lane frag.
// ushort idx(m,c) = (m>>4)*1024 + (c>>5)*512 + ((c>>3)&3)*128 + (m&15)*8 + (c&7)
#define OFF_YK  983584                    // 20*32768 ushorts = 327680 floats
#define OFF_XK  (OFF_YK + 327680)
#define OFF_PM  (OFF_XK + 327680)         // per-block colmax: [pair][slab][512]

typedef __attribute__((ext_vector_type(8))) short bf16x8;
typedef __attribute__((ext_vector_type(4))) float f32x4;

__device__ __forceinline__ int gidx(int n, int c, int h, int w, int d) {
  return (((n * C_ + c) * HWD + h) * HWD + w) * HWD + d;
}

__device__ __forceinline__ unsigned short f2bf(float f) {  // RNE bf16
  unsigned u = __float_as_uint(f);
  u += 0x7FFFu + ((u >> 16) & 1u);
  return (unsigned short)(u >> 16);
}

__device__ __forceinline__ int fidx(int m, int c) {  // fragment-major ushort idx
  return ((m >> 4) << 10) + ((c >> 5) << 9) + (((c >> 3) & 3) << 7) +
         ((m & 15) << 3) + (c & 7);
}

// ---- kernel 1: gather x,y -> compact fp32; y means; zero final counters ---
__global__ void k_gather(const float* __restrict__ x, const float* __restrict__ y,
                         const int* __restrict__ hi, const int* __restrict__ wi,
                         const int* __restrict__ di, float* __restrict__ ws) {
  int b = blockIdx.x, t = threadIdx.x;
  int lane = t & 63, wv = t >> 6;
  __shared__ float red[4];
  if (b == 0 && t < ZERO_N) ws[OFF_CNT + t] = 0.f;   // zero CNT+ALL+PL
  int which = b >= 480;                              // 0 = y, 1 = x
  int r = which ? b - 480 : b;
  int s = r / C_, c = r % C_;
  const float* src = which ? x : y;
  int h0 = hi[s] - PADK, w0 = wi[s] - PADK, d0 = di[s] - PADK;
  float* dst = ws + (which ? OFF_GX : OFF_GY) + (s * 96 + 2 * c) * 512;
  float sum = 0.f;
#pragma unroll
  for (int j = 0; j < 4; ++j) {
    int i = t + 256 * j;
    int n = i >> 9, m = i & 511;
    float v = src[gidx(n, c, h0 + (m >> 6), w0 + ((m >> 3) & 7), d0 + (m & 7))];
    dst[n * 512 + m] = v;
    sum += v;
  }
  if (!which) {
#pragma unroll
    for (int off = 32; off; off >>= 1) sum += __shfl_xor(sum, off);
    if (lane == 0) red[wv] = sum;
    __syncthreads();
    if (t == 0)
      ws[OFF_MU + s * C_ + c] =
          (red[0] + red[1] + red[2] + red[3]) * (1.0f / 1024.0f);
  }
}

// ---- kernel 2: center + normalize -> bf16 FRAGMENT-MAJOR ------------------
__global__ void k_nc(float* __restrict__ ws) {
  int g = blockIdx.x * 256 + threadIdx.x;   // 0..81919
  int col = g >> 2;                         // 0..20479
  int q = threadIdx.x & 3;
  int which = col >= 10240;                 // 0 = y, 1 = x
  int cix = which ? col - 10240 : col;
  int pair = cix >> 9, m = cix & 511;
  int s = pair >> 1, n = pair & 1;
  const float* base = ws + (which ? OFF_GX : OFF_GY) + (s * 96 + n) * 512 + m;
  const float* mus = ws + OFF_MU + s * C_;
  int c0 = q * 12;
  float v[12], ss = 0.f;
#pragma unroll
  for (int j = 0; j < 12; ++j) {
    v[j] = base[(c0 + j) * 1024] - mus[c0 + j];
    ss += v[j] * v[j];
  }
  ss += __shfl_xor(ss, 1);
  ss += __shfl_xor(ss, 2);
  float sc = 1.0f / fmaxf(sqrtf(ss), 1e-12f);
  unsigned short* dstk = (unsigned short*)(ws + (which ? OFF_XK : OFF_YK)) +
                         pair * 32768;
#pragma unroll
  for (int j = 0; j < 12; ++j) dstk[fidx(m, c0 + j)] = f2bf(v[j] * sc);
  if (q == 3) {                         // zero pad k = 48..63
#pragma unroll
    for (int c = 48; c < 64; ++c) dstk[fidx(m, c)] = 0;
  }
}

// ---- kernel 3: MFMA dist + softmax; PLAIN-STORE slab colmax (no atomics,
//      no fences, no tail). 640 blocks x 64 thr; block = (pair, 16-row slab).
// C/D mapping per m89: col = lane&15, row = (lane>>4)*4 + reg.
__global__ __launch_bounds__(64, 2) void k_mm(float* __restrict__ ws) {
  int b = blockIdx.x;
  int pair = b >> 5, slab = b & 31;
  int lane = threadIdx.x;

  const unsigned short* xf =
      (const unsigned short*)(ws + OFF_XK) + pair * 32768;
  const unsigned short* yf =
      (const unsigned short*)(ws + OFF_YK) + pair * 32768;

  // A-frags: slab chunk, khalf 0/1 — coalesced 1KB loads
  bf16x8 a0 = *(const bf16x8*)(xf + slab * 1024 + lane * 8);
  bf16x8 a1 = *(const bf16x8*)(xf + slab * 1024 + 512 + lane * 8);

  f32x4 d[32];
#pragma unroll
  for (int ct = 0; ct < 32; ++ct) {    // 64 coalesced 1KB loads, independent
    bf16x8 b0 = *(const bf16x8*)(yf + ct * 1024 + lane * 8);
    bf16x8 b1 = *(const bf16x8*)(yf + ct * 1024 + 512 + lane * 8);
    f32x4 z = {0.f, 0.f, 0.f, 0.f};
    f32x4 dd = __builtin_amdgcn_mfma_f32_16x16x32_bf16(a0, b0, z, 0, 0, 0);
    d[ct] = __builtin_amdgcn_mfma_f32_16x16x32_bf16(a1, b1, dd, 0, 0, 0);
  }

  // epilogue: amax per row (dmin = 1 - amax) -> softmax -> slab colmax
  float am0 = -3.4e38f, am1 = -3.4e38f, am2 = -3.4e38f, am3 = -3.4e38f;
#pragma unroll
  for (int ct = 0; ct < 32; ++ct) {
    am0 = fmaxf(am0, d[ct][0]); am1 = fmaxf(am1, d[ct][1]);
    am2 = fmaxf(am2, d[ct][2]); am3 = fmaxf(am3, d[ct][3]);
  }
#pragma unroll
  for (int off = 1; off < 16; off <<= 1) {
    am0 = fmaxf(am0, __shfl_xor(am0, off));
    am1 = fmaxf(am1, __shfl_xor(am1, off));
    am2 = fmaxf(am2, __shfl_xor(am2, off));
    am3 = fmaxf(am3, __shfl_xor(am3, off));
  }
  float inv0 = 2.f / ((1.f - am0) + 1e-5f), c20 = 2.f - inv0;
  float inv1 = 2.f / ((1.f - am1) + 1e-5f), c21 = 2.f - inv1;
  float inv2 = 2.f / ((1.f - am2) + 1e-5f), c22 = 2.f - inv2;
  float inv3 = 2.f / ((1.f - am3) + 1e-5f), c23 = 2.f - inv3;
  float sm0 = 0.f, sm1 = 0.f, sm2 = 0.f, sm3 = 0.f;
#pragma unroll
  for (int ct = 0; ct < 32; ++ct) {    // logit = 2 - (1-a)*inv = c2 + a*inv
    float e0 = __expf(fmaf(d[ct][0], inv0, c20));
    float e1 = __expf(fmaf(d[ct][1], inv1, c21));
    float e2 = __expf(fmaf(d[ct][2], inv2, c22));
    float e3 = __expf(fmaf(d[ct][3], inv3, c23));
    d[ct][0] = e0; d[ct][1] = e1; d[ct][2] = e2; d[ct][3] = e3;
    sm0 += e0; sm1 += e1; sm2 += e2; sm3 += e3;
  }
#pragma unroll
  for (int off = 1; off < 16; off <<= 1) {
    sm0 += __shfl_xor(sm0, off); sm1 += __shfl_xor(sm1, off);
    sm2 += __shfl_xor(sm2, off); sm3 += __shfl_xor(sm3, off);
  }
  float rs0 = 1.f / sm0, rs1 = 1.f / sm1, rs2 = 1.f / sm2, rs3 = 1.f / sm3;
  float* pm = ws + OFF_PM + (pair * 32 + slab) * M_;
#pragma unroll
  for (int ct = 0; ct < 32; ++ct) {
    float cc = fmaxf(fmaxf(d[ct][0] * rs0, d[ct][1] * rs1),
                     fmaxf(d[ct][2] * rs2, d[ct][3] * rs3));
    cc = fmaxf(cc, __shfl_xor(cc, 16));
    cc = fmaxf(cc, __shfl_xor(cc, 32));  // max over this slab's 16 rows
    if (lane < 16) pm[ct * 16 + lane] = cc;   // plain coalesced store
  }
}

// ---- kernel 4: per-pair colmax-combine + loss; last pair writes out -------
// 20 blocks x 256 thr; block = pair. Kernel boundary = coherence for pm.
__global__ void k_final(float* __restrict__ ws, float* __restrict__ out) {
  int pair = blockIdx.x;
  int t = threadIdx.x, lane = t & 63, wv = t >> 6;
  __shared__ float red[4];
  __shared__ int lastflag;
  const float* pm = ws + OFF_PM + pair * 32 * M_;

  float m0 = 0.f, m1 = 0.f;
  for (int s = 0; s < 32; ++s) {       // coalesced: consecutive t -> consecutive
    m0 = fmaxf(m0, pm[s * M_ + t]);
    m1 = fmaxf(m1, pm[s * M_ + t + 256]);
  }
  float sum = m0 + m1;                 // per-thread partial of cx-sum
#pragma unroll
  for (int off = 32; off; off >>= 1) sum += __shfl_xor(sum, off);
  if (lane == 0) red[wv] = sum;
  if (t == 0) lastflag = 0;
  __syncthreads();
  if (t == 0) {
    float tot = red[0] + red[1] + red[2] + red[3];
    float loss = -logf(tot * (1.0f / 512.0f) + 1e-5f);
    atomicExch((unsigned*)(ws + OFF_PL) + pair, __float_as_uint(loss));
    __threadfence();
    unsigned dct = atomicAdd((unsigned*)(ws + OFF_ALL), 1u);
    if (dct == PAIRS - 1) lastflag = 1;
  }
  __syncthreads();
  if (lastflag && t < 32) {            // parallel 20-loss readback
    float v = (t < PAIRS)
                  ? __uint_as_float(atomicOr((unsigned*)(ws + OFF_PL) + t, 0u))
                  : 0.f;
#pragma unroll
    for (int off = 16; off; off >>= 1) v += __shfl_xor(v, off);
    if (t == 0) out[0] = v * (1.0f / (float)PAIRS);
  }
}

extern "C" void kernel_launch(void* const* d_in, const int* in_sizes, int n_in,
                              void* d_out, int out_size, void* d_ws, size_t ws_size,
                              hipStream_t stream) {
  const float* x = (const float*)d_in[0];
  const float* y = (const float*)d_in[1];
  const int* hi = (const int*)d_in[2];
  const int* wi = (const int*)d_in[3];
  const int* di = (const int*)d_in[4];
  float* ws = (float*)d_ws;
  float* out = (float*)d_out;

  k_gather<<<960, 256, 0, stream>>>(x, y, hi, wi, di, ws);
  k_nc<<<320, 256, 0, stream>>>(ws);
  k_mm<<<PAIRS * 32, 64, 0, stream>>>(ws);
  k_final<<<PAIRS, 256, 0, stream>>>(ws, out);
}